// Round 1
// baseline (1895.622 us; speedup 1.0000x reference)
//
#include <hip/hip_runtime.h>
#include <stdint.h>

#define NCOLS     32768
#define K_TOP     64
#define BLOCK     1024
#define VPT       32          // values per thread = NCOLS / BLOCK
#define F4_PER_T  8           // float4 loads per thread
#define CAND_CAP  4096        // LDS candidate capacity (32 KB)

// Order-preserving map fp32 -> u32 (total order, matches float compare)
__device__ __forceinline__ unsigned orderable(float f) {
    unsigned s = __float_as_uint(f);
    return (s & 0x80000000u) ? ~s : (s | 0x80000000u);
}

__device__ __forceinline__ int block_reduce_sum(int v, int* s_part) {
    #pragma unroll
    for (int off = 32; off > 0; off >>= 1) v += __shfl_down(v, off);
    const int wid  = threadIdx.x >> 6;
    const int lane = threadIdx.x & 63;
    __syncthreads();                       // protect s_part from previous use
    if (lane == 0) s_part[wid] = v;
    __syncthreads();
    if (wid == 0) {
        int x = (lane < 16) ? s_part[lane] : 0;
        #pragma unroll
        for (int off = 8; off > 0; off >>= 1) x += __shfl_down(x, off);
        if (lane == 0) s_part[0] = x;
    }
    __syncthreads();
    return s_part[0];
}

__global__ __launch_bounds__(BLOCK, 4)
void topk64_scatter_kernel(const float* __restrict__ x, float* __restrict__ out) {
    __shared__ unsigned s_cnt;
    __shared__ uint2    s_cand[CAND_CAP];
    __shared__ int      s_part[16];
    __shared__ uint2    s_thr;

    const int tid = threadIdx.x;
    const long long row = blockIdx.x;
    const float4* __restrict__ xin  = (const float4*)(x   + row * (long long)NCOLS);
    float4* __restrict__       xout = (float4*)      (out + row * (long long)NCOLS);

    // ---- load row, 32 elements/thread, coalesced float4 ----
    unsigned u[VPT];
    #pragma unroll
    for (int i = 0; i < F4_PER_T; ++i) {
        float4 v = xin[i * BLOCK + tid];
        u[i*4+0] = orderable(v.x);
        u[i*4+1] = orderable(v.y);
        u[i*4+2] = orderable(v.z);
        u[i*4+3] = orderable(v.w);
    }

    // ---- candidate prefilter threshold ----
    // orderable(2.5f) = 0xC0200000. For N(0,1) rows the 64th max is ~2.9,
    // expected candidate count ~203 (binomial std ~14) -> always in [64, 4096].
    unsigned U = 0xC0200000u;
    int n;
    {
        int c = 0;
        #pragma unroll
        for (int k = 0; k < VPT; ++k) c += (u[k] >= U) ? 1 : 0;
        n = block_reduce_sum(c, s_part);
    }
    if (n < K_TOP || n > CAND_CAP) {
        // General-correctness fallback (unreachable for this input):
        // binary search largest U with count(>=U) >= K_TOP.
        unsigned lo = 0u, hi = 0xFFFFFFFFu;
        while (hi - lo > 1u) {
            unsigned mid = lo + ((hi - lo) >> 1);
            int c = 0;
            #pragma unroll
            for (int k = 0; k < VPT; ++k) c += (u[k] >= mid) ? 1 : 0;
            int cc = block_reduce_sum(c, s_part);
            if (cc >= K_TOP) lo = mid; else hi = mid;
        }
        {
            int c = 0;
            #pragma unroll
            for (int k = 0; k < VPT; ++k) c += (u[k] >= hi) ? 1 : 0;
            int cc = block_reduce_sum(c, s_part);
            U = (cc >= K_TOP) ? hi : lo;
        }
        {
            int c = 0;
            #pragma unroll
            for (int k = 0; k < VPT; ++k) c += (u[k] >= U) ? 1 : 0;
            n = block_reduce_sum(c, s_part);
        }
    }

    // ---- append candidates (key, idx) to LDS ----
    if (tid == 0) s_cnt = 0;
    __syncthreads();
    #pragma unroll
    for (int i = 0; i < F4_PER_T; ++i) {
        #pragma unroll
        for (int j = 0; j < 4; ++j) {
            const int k = i*4 + j;
            if (u[k] >= U) {
                unsigned p = atomicAdd(&s_cnt, 1u);
                if (p < CAND_CAP) {
                    s_cand[p] = make_uint2(u[k], (unsigned)((i * BLOCK + tid) * 4 + j));
                }
            }
        }
    }
    __syncthreads();
    int na = (int)s_cnt;
    if (na > CAND_CAP) na = CAND_CAP;

    // ---- find exact 64th-largest by composite key (value desc, index asc) ----
    for (int c = tid; c < na; c += BLOCK) {
        uint2 me = s_cand[c];
        int r = 0;
        for (int j = 0; j < na; ++j) {       // LDS broadcast reads
            uint2 o = s_cand[j];
            r += (o.x > me.x || (o.x == me.x && o.y < me.y)) ? 1 : 0;
        }
        if (r == K_TOP - 1) s_thr = me;      // exactly one writer
    }
    __syncthreads();
    const unsigned Tu = s_thr.x;
    const unsigned Ti = s_thr.y;

    // ---- write output: relu(x) at selected positions, 0 elsewhere ----
    #pragma unroll
    for (int i = 0; i < F4_PER_T; ++i) {
        float4 o;
        float vals[4];
        #pragma unroll
        for (int j = 0; j < 4; ++j) {
            const int k = i*4 + j;
            const unsigned idx = (unsigned)((i * BLOCK + tid) * 4 + j);
            const bool sel = (u[k] > Tu) || (u[k] == Tu && idx <= Ti);
            // relu: positive floats have key > orderable(+0) = 0x80000000
            vals[j] = (sel && u[k] > 0x80000000u)
                        ? __uint_as_float(u[k] & 0x7FFFFFFFu) : 0.0f;
        }
        o.x = vals[0]; o.y = vals[1]; o.z = vals[2]; o.w = vals[3];
        xout[i * BLOCK + tid] = o;
    }
}

extern "C" void kernel_launch(void* const* d_in, const int* in_sizes, int n_in,
                              void* d_out, int out_size, void* d_ws, size_t ws_size,
                              hipStream_t stream) {
    const float* x = (const float*)d_in[0];
    float* out = (float*)d_out;
    const int rows = in_sizes[0] / NCOLS;
    topk64_scatter_kernel<<<dim3(rows), dim3(BLOCK), 0, stream>>>(x, out);
}